// Round 6
// baseline (677.015 us; speedup 1.0000x reference)
//
#include <hip/hip_runtime.h>
#include <stdint.h>

typedef unsigned short u16;
typedef __attribute__((ext_vector_type(8))) short bf16x8;   // 8 bf16 = 4 VGPRs
typedef __attribute__((ext_vector_type(4))) float f32x4;

#define NUM_B 2
#define SEQ   2048
#define SEQP  2080      // padded V row stride (breaks 4KB L2 aliasing)
#define NH    16
#define HD    128
#define EMB   2048      // NH*HD
#define N3    6144      // 3*EMB
#define MM    4096      // NUM_B*SEQ
#define WQ    32        // flash q-rows per wave (= per block)
#define KT    32        // flash keys per k-tile
#define NTILE (SEQ / KT)

__device__ __forceinline__ u16 f2bf(float f) {
  union { float f; unsigned u; } c; c.f = f;
  return (u16)((c.u + 0x7FFFu + ((c.u >> 16) & 1u)) >> 16);   // RNE
}
__device__ __forceinline__ void async16(const void* g, void* l) {
  __builtin_amdgcn_global_load_lds(
      (const __attribute__((address_space(1))) void*)g,
      (__attribute__((address_space(3))) void*)l, 16, 0, 0);
}

// ---------------- prep kernels ----------------

__global__ void k_cvt_bf16(const float* __restrict__ in, u16* __restrict__ out, int n4) {
  int i = blockIdx.x * blockDim.x + threadIdx.x;
  if (i >= n4) return;
  const float4 v = ((const float4*)in)[i];
  ushort4 o;
  o.x = f2bf(v.x); o.y = f2bf(v.y); o.z = f2bf(v.z); o.w = f2bf(v.w);
  ((ushort4*)out)[i] = o;
}

// W [EMB][N3] fp32 -> Wt [N3][EMB] bf16
__global__ void k_transpose_w(const float* __restrict__ W, u16* __restrict__ Wt) {
  __shared__ float t[32][33];
  int n0 = blockIdx.x * 32, k0 = blockIdx.y * 32;
  int tx = threadIdx.x, ty = threadIdx.y;
  #pragma unroll
  for (int i = ty; i < 32; i += 8)
    t[i][tx] = W[(size_t)(k0 + i) * N3 + n0 + tx];
  __syncthreads();
  #pragma unroll
  for (int i = ty; i < 32; i += 8)
    Wt[(size_t)(n0 + i) * EMB + k0 + tx] = f2bf(t[tx][i]);
}

// sincos table for t = s*HD + d; double-precision sincos matches numpy fp32 tables
__global__ void k_sincos(float2* __restrict__ tab) {
  int i = blockIdx.x * blockDim.x + threadIdx.x;   // 0 .. SEQ*HD-1
  double t = (double)i;
  tab[i] = make_float2((float)cos(t), (float)sin(t));
}

// ---------------- QKV GEMM (round-4 version: 16x16x32, 144 us known-good) ----------------
__global__ __launch_bounds__(256, 2) void k_gemm_qkv(
    const u16* __restrict__ xb, const u16* __restrict__ wt,
    const float* __restrict__ bias, const float2* __restrict__ tab,
    u16* __restrict__ qb, u16* __restrict__ kb, u16* __restrict__ vbt)
{
  __shared__ __align__(16) u16 lsA[128 * 32];
  __shared__ __align__(16) u16 lsB[128 * 32];
  const int tid = threadIdx.x;
  const int wave = tid >> 6, lane = tid & 63;
  const int lq = lane & 15, lr = lane >> 4;
  const int m0 = blockIdx.y * 128, n0 = blockIdx.x * 128;

  f32x4 acc[2][8];
  #pragma unroll
  for (int i = 0; i < 2; ++i)
    #pragma unroll
    for (int j = 0; j < 8; ++j)
      acc[i][j] = f32x4{0.f, 0.f, 0.f, 0.f};

  for (int kt = 0; kt < EMB; kt += 32) {
    __syncthreads();
    #pragma unroll
    for (int i = 0; i < 2; ++i) {
      int c = tid + i * 256;          // 16B chunk; row = c>>2, koff = (c&3)*8
      async16(xb + (size_t)(m0 + (c >> 2)) * EMB + kt + (c & 3) * 8, lsA + c * 8);
      async16(wt + (size_t)(n0 + (c >> 2)) * EMB + kt + (c & 3) * 8, lsB + c * 8);
    }
    __syncthreads();
    bf16x8 af[2], bfr[8];
    #pragma unroll
    for (int i = 0; i < 2; ++i)
      af[i] = *(const bf16x8*)(lsA + (wave * 32 + i * 16 + lq) * 32 + lr * 8);
    #pragma unroll
    for (int j = 0; j < 8; ++j)
      bfr[j] = *(const bf16x8*)(lsB + (j * 16 + lq) * 32 + lr * 8);
    #pragma unroll
    for (int i = 0; i < 2; ++i)
      #pragma unroll
      for (int j = 0; j < 8; ++j)
        acc[i][j] = __builtin_amdgcn_mfma_f32_16x16x32_bf16(af[i], bfr[j], acc[i][j], 0, 0, 0);
  }

  const int w = n0 >> 11;              // 0=q, 1=k, 2=v
  const int h = (n0 & 2047) >> 7;
  float bb[8];
  #pragma unroll
  for (int j = 0; j < 8; ++j) bb[j] = bias[n0 + j * 16 + lq];

  if (w == 2) {
    // V: transpose to [B,H,D,SEQP], pack 4 consecutive s per 8B store
    #pragma unroll
    for (int i = 0; i < 2; ++i)
      #pragma unroll
      for (int j = 0; j < 8; ++j) {
        int d = j * 16 + lq;
        int mg0 = m0 + wave * 32 + i * 16 + lr * 4;
        int b = mg0 >> 11, s0 = mg0 & 2047;
        ushort4 pk;
        pk.x = f2bf(acc[i][j][0] + bb[j]);
        pk.y = f2bf(acc[i][j][1] + bb[j]);
        pk.z = f2bf(acc[i][j][2] + bb[j]);
        pk.w = f2bf(acc[i][j][3] + bb[j]);
        *(ushort4*)(vbt + ((size_t)(b * NH + h) * HD + d) * SEQP + s0) = pk;
      }
  } else {
    u16* basep = (w == 0) ? qb : kb;
    const float qs = (w == 0) ? 0.12751569843736827f : 1.0f;  // log2(e)/sqrt(128) into q
    #pragma unroll
    for (int i = 0; i < 2; ++i)
      #pragma unroll
      for (int jp = 0; jp < 4; ++jp)
        #pragma unroll
        for (int r = 0; r < 4; ++r) {
          int row = wave * 32 + i * 16 + lr * 4 + r;
          int mg = m0 + row;
          int b = mg >> 11, s = mg & 2047;
          int d1 = jp * 16 + lq;                      // < 64; pair is d1+64
          float c1 = acc[i][jp][r]     + bb[jp];
          float c2 = acc[i][jp + 4][r] + bb[jp + 4];
          float2 s1 = tab[s * HD + d1];
          float2 s2 = tab[s * HD + d1 + 64];
          u16* dst = basep + ((size_t)(b * NH + h) * SEQ + s) * HD;
          dst[d1]      = f2bf((c1 * s1.x - c2 * s1.y) * qs);
          dst[d1 + 64] = f2bf((c2 * s2.x + c1 * s2.y) * qs);
        }
  }
}

// ---------------- flash attention v4: register-direct K/V, barrier-free ----------------
// grid (SEQ/WQ=64, B*H=32) = 2048 single-wave blocks = 8 waves/CU = 2/SIMD.
// K and V fragments are 16B-contiguous in global (kb [B,H,S,D]; vbt [B,H,D,SEQP])
// -> loaded straight to registers (global_load_dwordx4), K pipelined one tile
// ahead via unroll-by-2 parity. No __syncthreads at all; only per-wave lsP
// (C-layout -> A-layout) round-trip, synced by lgkmcnt. Tile order staggered
// per block (fixed-base softmax sum is order-independent) to spread L2.
__global__ __launch_bounds__(64, 2) void k_flash(
    const u16* __restrict__ qb, const u16* __restrict__ kb,
    const u16* __restrict__ vbt, float* __restrict__ out)
{
  __shared__ __align__(16) u16 lsP[WQ * KT];   // [qrow][key], 8B-grp ^= row&6 (2 KB)

  const int lane = threadIdx.x;           // 0..63
  const int lq = lane & 15, lr = lane >> 4;
  const int q0 = blockIdx.x * WQ;
  const int bh = blockIdx.y;
  const u16* Qg = qb + ((size_t)bh * SEQ + q0) * HD;
  const u16* Kg = kb + (size_t)bh * SEQ * HD;
  const u16* Vg = vbt + (size_t)bh * HD * SEQP;
  const int start = blockIdx.x & (NTILE - 1);   // stagger k-tile order

  // Q fragments (B-operand: lane holds Q[q=qq*16+lq][d=ks*32+lr*8 ..+7])
  bf16x8 qf[2][4];
  #pragma unroll
  for (int qq = 0; qq < 2; ++qq)
    #pragma unroll
    for (int ks = 0; ks < 4; ++ks)
      qf[qq][ks] = *(const bf16x8*)(Qg + (size_t)(qq * 16 + lq) * HD + ks * 32 + lr * 8);

  f32x4 acc_o[2][8];
  float lsum[2] = {0.f, 0.f};
  #pragma unroll
  for (int mb = 0; mb < 2; ++mb)
    #pragma unroll
    for (int nb = 0; nb < 8; ++nb) acc_o[mb][nb] = f32x4{0.f, 0.f, 0.f, 0.f};

  // K fragment loader (A-operand: lane holds K[key=kbi*16+lq][d=ks*32+lr*8 ..+7])
  auto loadK = [&](int tile, bf16x8 (&kf)[2][4]) {
    const int k0 = tile * KT;
    #pragma unroll
    for (int kbi = 0; kbi < 2; ++kbi)
      #pragma unroll
      for (int ks = 0; ks < 4; ++ks)
        kf[kbi][ks] = *(const bf16x8*)(Kg + (size_t)(k0 + kbi * 16 + lq) * HD + ks * 32 + lr * 8);
  };

  // one k-tile step: compute with kfc, prefetch nextTile into kfn
  auto step = [&](int tile, int nextTile, bf16x8 (&kfc)[2][4], bf16x8 (&kfn)[2][4], bool pref) {
    // V fragments for this tile (B-operand: lane holds V[key=k0+lr*8 ..+7][d=nb*16+lq])
    const int k0 = tile * KT;
    bf16x8 bv[8];
    #pragma unroll
    for (int nb = 0; nb < 8; ++nb)
      bv[nb] = *(const bf16x8*)(Vg + (size_t)(nb * 16 + lq) * SEQP + k0 + lr * 8);

    // S^T = K Q^T : 32 keys x 32 q-rows
    f32x4 sacc[2][2];
    #pragma unroll
    for (int kbi = 0; kbi < 2; ++kbi)
      #pragma unroll
      for (int qq = 0; qq < 2; ++qq) sacc[kbi][qq] = f32x4{0.f, 0.f, 0.f, 0.f};
    #pragma unroll
    for (int ks = 0; ks < 4; ++ks)
      #pragma unroll
      for (int kbi = 0; kbi < 2; ++kbi)
        #pragma unroll
        for (int qq = 0; qq < 2; ++qq)
          sacc[kbi][qq] = __builtin_amdgcn_mfma_f32_16x16x32_bf16(kfc[kbi][ks], qf[qq][ks], sacc[kbi][qq], 0, 0, 0);

    if (pref) loadK(nextTile, kfn);     // K for next tile rides over exp+PV

    // P = exp2(S) (log2e folded into q); packed b64 writes (4 consecutive keys/lane)
    #pragma unroll
    for (int kbi = 0; kbi < 2; ++kbi)
      #pragma unroll
      for (int qq = 0; qq < 2; ++qq) {
        float p0 = __builtin_amdgcn_exp2f(sacc[kbi][qq][0]);
        float p1 = __builtin_amdgcn_exp2f(sacc[kbi][qq][1]);
        float p2 = __builtin_amdgcn_exp2f(sacc[kbi][qq][2]);
        float p3 = __builtin_amdgcn_exp2f(sacc[kbi][qq][3]);
        lsum[qq] += (p0 + p1) + (p2 + p3);
        int row = qq * 16 + lq;
        int g = kbi * 4 + lr;
        int gp = g ^ (row & 6);
        uint2 pk;
        pk.x = (uint32_t)f2bf(p0) | ((uint32_t)f2bf(p1) << 16);
        pk.y = (uint32_t)f2bf(p2) | ((uint32_t)f2bf(p3) << 16);
        *(uint2*)(lsP + row * KT + gp * 4) = pk;
      }

    // O += P V  (per-wave lsP RAW handled by lgkmcnt)
    bf16x8 ap[2];
    #pragma unroll
    for (int mb = 0; mb < 2; ++mb) {
      int row = mb * 16 + lq;
      int gp = (2 * lr) ^ (row & 6);
      ap[mb] = *(const bf16x8*)(lsP + row * KT + gp * 4);
    }
    #pragma unroll
    for (int nb = 0; nb < 8; ++nb)
      #pragma unroll
      for (int mb = 0; mb < 2; ++mb)
        acc_o[mb][nb] = __builtin_amdgcn_mfma_f32_16x16x32_bf16(ap[mb], bv[nb], acc_o[mb][nb], 0, 0, 0);
  };

  bf16x8 kfA[2][4], kfB[2][4];
  loadK(start, kfA);
  for (int tt = 0; tt < NTILE; tt += 2) {
    int t0 = (start + tt)     & (NTILE - 1);
    int t1 = (start + tt + 1) & (NTILE - 1);
    int t2 = (start + tt + 2) & (NTILE - 1);
    step(t0, t1, kfA, kfB, true);
    step(t1, t2, kfB, kfA, tt + 2 < NTILE);
  }

  // epilogue: reduce row sums over lr groups, divide, store
  float inv[2];
  #pragma unroll
  for (int qq = 0; qq < 2; ++qq) {
    float s = lsum[qq];
    s += __shfl_xor(s, 16);
    s += __shfl_xor(s, 32);
    inv[qq] = 1.0f / s;
  }
  const int b = bh >> 4, h = bh & 15;
  #pragma unroll
  for (int mb = 0; mb < 2; ++mb)
    #pragma unroll
    for (int r = 0; r < 4; ++r) {
      float iv = __shfl(inv[mb], lr * 4 + r);      // lane lr*4+r holds q-row mb*16+lr*4+r
      int row = mb * 16 + lr * 4 + r;
      int sq = q0 + row;
      float* op = out + (((size_t)b * SEQ + sq) * NH + h) * HD;
      #pragma unroll
      for (int nb = 0; nb < 8; ++nb)
        op[nb * 16 + lq] = acc_o[mb][nb][r] * iv;
    }
}

// ---------------- launch ----------------

extern "C" void kernel_launch(void* const* d_in, const int* in_sizes, int n_in,
                              void* d_out, int out_size, void* d_ws, size_t ws_size,
                              hipStream_t stream) {
  (void)in_sizes; (void)n_in; (void)out_size; (void)ws_size;
  const float* x    = (const float*)d_in[0];
  const float* W    = (const float*)d_in[1];
  const float* bias = (const float*)d_in[2];
  float* out = (float*)d_out;

  char* p = (char*)d_ws;
  u16* xb  = (u16*)p;  p += (size_t)MM * EMB * 2;                     // 16.8 MB
  u16* wt  = (u16*)p;  p += (size_t)N3 * EMB * 2;                     // 25.2 MB
  u16* qb  = (u16*)p;  p += (size_t)NUM_B * NH * SEQ * HD * 2;        // 16.8 MB
  u16* kb  = (u16*)p;  p += (size_t)NUM_B * NH * SEQ * HD * 2;        // 16.8 MB
  u16* vbt = (u16*)p;  p += (size_t)NUM_B * NH * HD * SEQP * 2;       // 17.0 MB
  float2* tab = (float2*)p;                                           // 2.1 MB

  k_cvt_bf16<<<(MM * EMB / 4 + 255) / 256, 256, 0, stream>>>(x, xb, MM * EMB / 4);
  k_transpose_w<<<dim3(N3 / 32, EMB / 32), dim3(32, 8), 0, stream>>>(W, wt);
  k_sincos<<<(SEQ * HD) / 256, 256, 0, stream>>>(tab);
  k_gemm_qkv<<<dim3(N3 / 128, MM / 128), 256, 0, stream>>>(xb, wt, bias, tab, qb, kb, vbt);
  k_flash<<<dim3(SEQ / WQ, NUM_B * NH), 64, 0, stream>>>(qb, kb, vbt, out);
}

// Round 7
// 356.627 us; speedup vs baseline: 1.8984x; 1.8984x over previous
//
#include <hip/hip_runtime.h>
#include <stdint.h>

typedef unsigned short u16;
typedef __attribute__((ext_vector_type(8))) short bf16x8;   // 8 bf16 = 4 VGPRs
typedef __attribute__((ext_vector_type(4))) float f32x4;

#define NUM_B 2
#define SEQ   2048
#define SEQP  2080      // padded V row stride
#define NH    16
#define HD    128
#define EMB   2048      // NH*HD
#define N3    6144      // 3*EMB
#define MM    4096      // NUM_B*SEQ
#define QT    64        // flash q-rows per block (2 waves)
#define WQ    32        // flash q-rows per wave
#define KT    32        // flash keys per k-tile
#define NTILE (SEQ / KT)

__device__ __forceinline__ u16 f2bf(float f) {
  union { float f; unsigned u; } c; c.f = f;
  return (u16)((c.u + 0x7FFFu + ((c.u >> 16) & 1u)) >> 16);   // RNE
}
__device__ __forceinline__ void async16(const void* g, void* l) {
  __builtin_amdgcn_global_load_lds(
      (const __attribute__((address_space(1))) void*)g,
      (__attribute__((address_space(3))) void*)l, 16, 0, 0);
}

// ---------------- prep kernels ----------------

__global__ void k_cvt_bf16(const float* __restrict__ in, u16* __restrict__ out, int n4) {
  int i = blockIdx.x * blockDim.x + threadIdx.x;
  if (i >= n4) return;
  const float4 v = ((const float4*)in)[i];
  ushort4 o;
  o.x = f2bf(v.x); o.y = f2bf(v.y); o.z = f2bf(v.z); o.w = f2bf(v.w);
  ((ushort4*)out)[i] = o;
}

// W [EMB][N3] fp32 -> Wt [N3][EMB] bf16
__global__ void k_transpose_w(const float* __restrict__ W, u16* __restrict__ Wt) {
  __shared__ float t[32][33];
  int n0 = blockIdx.x * 32, k0 = blockIdx.y * 32;
  int tx = threadIdx.x, ty = threadIdx.y;
  #pragma unroll
  for (int i = ty; i < 32; i += 8)
    t[i][tx] = W[(size_t)(k0 + i) * N3 + n0 + tx];
  __syncthreads();
  #pragma unroll
  for (int i = ty; i < 32; i += 8)
    Wt[(size_t)(n0 + i) * EMB + k0 + tx] = f2bf(t[tx][i]);
}

// sincos table for t = s*HD + d; double-precision sincos matches numpy fp32 tables
__global__ void k_sincos(float2* __restrict__ tab) {
  int i = blockIdx.x * blockDim.x + threadIdx.x;   // 0 .. SEQ*HD-1
  double t = (double)i;
  tab[i] = make_float2((float)cos(t), (float)sin(t));
}

// ---------------- QKV GEMM (round-4 version: 16x16x32, 144 us known-good) ----------------
__global__ __launch_bounds__(256, 2) void k_gemm_qkv(
    const u16* __restrict__ xb, const u16* __restrict__ wt,
    const float* __restrict__ bias, const float2* __restrict__ tab,
    u16* __restrict__ qb, u16* __restrict__ kb, u16* __restrict__ vbt)
{
  __shared__ __align__(16) u16 lsA[128 * 32];
  __shared__ __align__(16) u16 lsB[128 * 32];
  const int tid = threadIdx.x;
  const int wave = tid >> 6, lane = tid & 63;
  const int lq = lane & 15, lr = lane >> 4;
  const int m0 = blockIdx.y * 128, n0 = blockIdx.x * 128;

  f32x4 acc[2][8];
  #pragma unroll
  for (int i = 0; i < 2; ++i)
    #pragma unroll
    for (int j = 0; j < 8; ++j)
      acc[i][j] = f32x4{0.f, 0.f, 0.f, 0.f};

  for (int kt = 0; kt < EMB; kt += 32) {
    __syncthreads();
    #pragma unroll
    for (int i = 0; i < 2; ++i) {
      int c = tid + i * 256;          // 16B chunk; row = c>>2, koff = (c&3)*8
      async16(xb + (size_t)(m0 + (c >> 2)) * EMB + kt + (c & 3) * 8, lsA + c * 8);
      async16(wt + (size_t)(n0 + (c >> 2)) * EMB + kt + (c & 3) * 8, lsB + c * 8);
    }
    __syncthreads();
    bf16x8 af[2], bfr[8];
    #pragma unroll
    for (int i = 0; i < 2; ++i)
      af[i] = *(const bf16x8*)(lsA + (wave * 32 + i * 16 + lq) * 32 + lr * 8);
    #pragma unroll
    for (int j = 0; j < 8; ++j)
      bfr[j] = *(const bf16x8*)(lsB + (j * 16 + lq) * 32 + lr * 8);
    #pragma unroll
    for (int i = 0; i < 2; ++i)
      #pragma unroll
      for (int j = 0; j < 8; ++j)
        acc[i][j] = __builtin_amdgcn_mfma_f32_16x16x32_bf16(af[i], bfr[j], acc[i][j], 0, 0, 0);
  }

  const int w = n0 >> 11;              // 0=q, 1=k, 2=v
  const int h = (n0 & 2047) >> 7;
  float bb[8];
  #pragma unroll
  for (int j = 0; j < 8; ++j) bb[j] = bias[n0 + j * 16 + lq];

  if (w == 2) {
    // V: transpose to [B,H,D,SEQP], pack 4 consecutive s per 8B store
    #pragma unroll
    for (int i = 0; i < 2; ++i)
      #pragma unroll
      for (int j = 0; j < 8; ++j) {
        int d = j * 16 + lq;
        int mg0 = m0 + wave * 32 + i * 16 + lr * 4;
        int b = mg0 >> 11, s0 = mg0 & 2047;
        ushort4 pk;
        pk.x = f2bf(acc[i][j][0] + bb[j]);
        pk.y = f2bf(acc[i][j][1] + bb[j]);
        pk.z = f2bf(acc[i][j][2] + bb[j]);
        pk.w = f2bf(acc[i][j][3] + bb[j]);
        *(ushort4*)(vbt + ((size_t)(b * NH + h) * HD + d) * SEQP + s0) = pk;
      }
  } else {
    u16* basep = (w == 0) ? qb : kb;
    const float qs = (w == 0) ? 0.12751569843736827f : 1.0f;  // log2(e)/sqrt(128) into q
    #pragma unroll
    for (int i = 0; i < 2; ++i)
      #pragma unroll
      for (int jp = 0; jp < 4; ++jp)
        #pragma unroll
        for (int r = 0; r < 4; ++r) {
          int row = wave * 32 + i * 16 + lr * 4 + r;
          int mg = m0 + row;
          int b = mg >> 11, s = mg & 2047;
          int d1 = jp * 16 + lq;                      // < 64; pair is d1+64
          float c1 = acc[i][jp][r]     + bb[jp];
          float c2 = acc[i][jp + 4][r] + bb[jp + 4];
          float2 s1 = tab[s * HD + d1];
          float2 s2 = tab[s * HD + d1 + 64];
          u16* dst = basep + ((size_t)(b * NH + h) * SEQ + s) * HD;
          dst[d1]      = f2bf((c1 * s1.x - c2 * s1.y) * qs);
          dst[d1 + 64] = f2bf((c2 * s2.x + c1 * s2.y) * qs);
        }
  }
}

// ---------------- flash attention (round-4 structure + XCD-aware remap) ----------------
// 1D grid of 1024 two-wave blocks. Block i -> XCD i&7 (measured round-robin);
// remap gives each XCD its own 4 heads, with all 32 q-blocks of a head
// co-resident on that XCD marching through the same K/V tile sequence
// -> per-XCD L2 working set = 4 heads * 1 MB = 4 MB = L2 size; each staged
// tile is fetched once per XCD and L2-served to the other 31 blocks.
__global__ __launch_bounds__(128, 2) void k_flash(
    const u16* __restrict__ qb, const u16* __restrict__ kb,
    const u16* __restrict__ vbt, float* __restrict__ out)
{
  __shared__ __align__(16) u16 lsK[2][KT * HD];   // [key][d] 16B-grp ^= key&7    (8 KB x2)
  __shared__ __align__(16) u16 lsV[2][HD * KT];   // [d][key] 16B-grp ^= (d>>1)&3 (8 KB x2)
  __shared__ __align__(16) u16 lsP[2][WQ * KT];   // per-wave [qrow][key], 8B-grp ^= row&6

  const int tid = threadIdx.x;            // 0..127
  const int wave = tid >> 6, lane = tid & 63;
  const int lq = lane & 15, lr = lane >> 4;
  const int i = blockIdx.x;               // 0..1023
  const int xcd = i & 7, j = i >> 3;      // j: 0..127
  const int bh = xcd * 4 + (j >> 5);      // 4 heads per XCD
  const int q0 = (j & 31) * QT;
  const u16* Qg = qb + ((size_t)bh * SEQ + q0 + wave * WQ) * HD;
  const u16* Kg = kb + (size_t)bh * SEQ * HD;
  const u16* Vg = vbt + (size_t)bh * HD * SEQP;

  auto stage = [&](int tile, int buf) {
    const int k0 = tile * KT;
    #pragma unroll
    for (int ii = 0; ii < 4; ++ii) {
      int c = tid + ii * 128;
      int key = c >> 4, grp = c & 15;
      async16(Kg + (size_t)(k0 + key) * HD + ((grp ^ (key & 7)) * 8), lsK[buf] + c * 8);
    }
    #pragma unroll
    for (int ii = 0; ii < 4; ++ii) {
      int c = tid + ii * 128;
      int d = c >> 2, g2 = c & 3;
      async16(Vg + (size_t)d * SEQP + k0 + ((g2 ^ ((d >> 1) & 3)) * 8), lsV[buf] + c * 8);
    }
  };

  stage(0, 0);

  bf16x8 qf[2][4];
  #pragma unroll
  for (int qq = 0; qq < 2; ++qq)
    #pragma unroll
    for (int ks = 0; ks < 4; ++ks)
      qf[qq][ks] = *(const bf16x8*)(Qg + (size_t)(qq * 16 + lq) * HD + ks * 32 + lr * 8);

  f32x4 acc_o[2][8];
  float lsum[2] = {0.f, 0.f};
  #pragma unroll
  for (int mb = 0; mb < 2; ++mb)
    #pragma unroll
    for (int nb = 0; nb < 8; ++nb) acc_o[mb][nb] = f32x4{0.f, 0.f, 0.f, 0.f};

  for (int t = 0; t < NTILE; ++t) {
    const int p = t & 1;
    __syncthreads();                 // drains stage(t); all waves done with buf 1-p
    if (t + 1 < NTILE) stage(t + 1, 1 - p);

    // S^T = K Q^T : 32 keys x 32 q-rows per wave
    f32x4 sacc[2][2];
    #pragma unroll
    for (int kbi = 0; kbi < 2; ++kbi)
      #pragma unroll
      for (int qq = 0; qq < 2; ++qq) sacc[kbi][qq] = f32x4{0.f, 0.f, 0.f, 0.f};
    #pragma unroll
    for (int ks = 0; ks < 4; ++ks) {
      bf16x8 kf[2];
      #pragma unroll
      for (int kbi = 0; kbi < 2; ++kbi) {
        int key = kbi * 16 + lq;
        int g = (ks * 4 + lr) ^ (key & 7);
        kf[kbi] = *(const bf16x8*)(lsK[p] + key * HD + g * 8);
      }
      #pragma unroll
      for (int kbi = 0; kbi < 2; ++kbi)
        #pragma unroll
        for (int qq = 0; qq < 2; ++qq)
          sacc[kbi][qq] = __builtin_amdgcn_mfma_f32_16x16x32_bf16(kf[kbi], qf[qq][ks], sacc[kbi][qq], 0, 0, 0);
    }

    // P = exp2(S) (log2e folded into q); packed b64 writes (4 consecutive keys/lane)
    #pragma unroll
    for (int kbi = 0; kbi < 2; ++kbi)
      #pragma unroll
      for (int qq = 0; qq < 2; ++qq) {
        float p0 = __builtin_amdgcn_exp2f(sacc[kbi][qq][0]);
        float p1 = __builtin_amdgcn_exp2f(sacc[kbi][qq][1]);
        float p2 = __builtin_amdgcn_exp2f(sacc[kbi][qq][2]);
        float p3 = __builtin_amdgcn_exp2f(sacc[kbi][qq][3]);
        lsum[qq] += (p0 + p1) + (p2 + p3);
        int row = qq * 16 + lq;
        int g = kbi * 4 + lr;
        int gp = g ^ (row & 6);
        uint2 pk;
        pk.x = (uint32_t)f2bf(p0) | ((uint32_t)f2bf(p1) << 16);
        pk.y = (uint32_t)f2bf(p2) | ((uint32_t)f2bf(p3) << 16);
        *(uint2*)(lsP[wave] + row * KT + gp * 4) = pk;
      }

    // O += P V
    bf16x8 ap[2];
    #pragma unroll
    for (int mb = 0; mb < 2; ++mb) {
      int row = mb * 16 + lq;
      int gp = (2 * lr) ^ (row & 6);
      ap[mb] = *(const bf16x8*)(lsP[wave] + row * KT + gp * 4);
    }
    #pragma unroll
    for (int nb = 0; nb < 8; ++nb) {
      int d = nb * 16 + lq;
      int g2 = lr ^ ((d >> 1) & 3);
      bf16x8 bv = *(const bf16x8*)(lsV[p] + d * KT + g2 * 8);
      #pragma unroll
      for (int mb = 0; mb < 2; ++mb)
        acc_o[mb][nb] = __builtin_amdgcn_mfma_f32_16x16x32_bf16(ap[mb], bv[0] == bv[0] ? bv : bv, acc_o[mb][nb], 0, 0, 0);
    }
  }

  float inv[2];
  #pragma unroll
  for (int qq = 0; qq < 2; ++qq) {
    float s = lsum[qq];
    s += __shfl_xor(s, 16);
    s += __shfl_xor(s, 32);
    inv[qq] = 1.0f / s;
  }
  const int b = bh >> 4, h = bh & 15;
  #pragma unroll
  for (int mb = 0; mb < 2; ++mb)
    #pragma unroll
    for (int r = 0; r < 4; ++r) {
      float iv = __shfl(inv[mb], lr * 4 + r);
      int row = wave * WQ + mb * 16 + lr * 4 + r;
      int sq = q0 + row;
      float* op = out + (((size_t)b * SEQ + sq) * NH + h) * HD;
      #pragma unroll
      for (int nb = 0; nb < 8; ++nb)
        op[nb * 16 + lq] = acc_o[mb][nb][r] * iv;
    }
}

// ---------------- launch ----------------

extern "C" void kernel_launch(void* const* d_in, const int* in_sizes, int n_in,
                              void* d_out, int out_size, void* d_ws, size_t ws_size,
                              hipStream_t stream) {
  (void)in_sizes; (void)n_in; (void)out_size; (void)ws_size;
  const float* x    = (const float*)d_in[0];
  const float* W    = (const float*)d_in[1];
  const float* bias = (const float*)d_in[2];
  float* out = (float*)d_out;

  char* p = (char*)d_ws;
  u16* xb  = (u16*)p;  p += (size_t)MM * EMB * 2;                     // 16.8 MB
  u16* wt  = (u16*)p;  p += (size_t)N3 * EMB * 2;                     // 25.2 MB
  u16* qb  = (u16*)p;  p += (size_t)NUM_B * NH * SEQ * HD * 2;        // 16.8 MB
  u16* kb  = (u16*)p;  p += (size_t)NUM_B * NH * SEQ * HD * 2;        // 16.8 MB
  u16* vbt = (u16*)p;  p += (size_t)NUM_B * NH * HD * SEQP * 2;       // 17.0 MB
  float2* tab = (float2*)p;                                           // 2.1 MB

  k_cvt_bf16<<<(MM * EMB / 4 + 255) / 256, 256, 0, stream>>>(x, xb, MM * EMB / 4);
  k_transpose_w<<<dim3(N3 / 32, EMB / 32), dim3(32, 8), 0, stream>>>(W, wt);
  k_sincos<<<(SEQ * HD) / 256, 256, 0, stream>>>(tab);
  k_gemm_qkv<<<dim3(N3 / 128, MM / 128), 256, 0, stream>>>(xb, wt, bias, tab, qb, kb, vbt);
  k_flash<<<SEQ / QT * NUM_B * NH, 128, 0, stream>>>(qb, kb, vbt, out);
}